// Round 8
// baseline (307.710 us; speedup 1.0000x reference)
//
#include <hip/hip_runtime.h>
#include <hip/hip_fp16.h>

#define N_NODES 10000
#define BATCH 8
#define FIN 128
#define UNITS 32
#define NH1 4

#define WAVE_FENCE() asm volatile("s_waitcnt lgkmcnt(0)" ::: "memory")

// f16(lo/hi of u32) * f32 + f32 -> f32, one VOP3P instruction (no separate cvt)
#define FMA_MIX_LO(acc, u, a) \
    asm("v_fma_mix_f32 %0, %1, %2, %0 op_sel:[0,0,0] op_sel_hi:[1,0,0]" \
        : "+v"(acc) : "v"(u), "v"(a))
#define FMA_MIX_HI(acc, u, a) \
    asm("v_fma_mix_f32 %0, %1, %2, %0 op_sel:[1,0,0] op_sel_hi:[1,0,0]" \
        : "+v"(acc) : "v"(u), "v"(a))

// ---------------- vec4 loader (f32 or f16 source) ----------------
template<typename T> struct Vec4Loader;
template<> struct Vec4Loader<float> {
    static __device__ inline float4 load(const float* p) { return *(const float4*)p; }
};
template<> struct Vec4Loader<__half> {
    static __device__ inline float4 load(const __half* p) {
        const __half2* p2 = (const __half2*)p;
        float2 a = __half22float2(p2[0]);
        float2 b = __half22float2(p2[1]);
        return make_float4(a.x, a.y, b.x, b.y);
    }
};

// ---------------- Wa precompute: Wa = W·a (folds logits into GEMM) ----------------
// Wa1[f][c]: c<4 -> sum_u W1[f][c][u]*a1s[c][u]; c>=4 -> same with a1d[c-4].
// Wa2[f][c]: c=0 -> sum_u W2[f][0][u]*a2s[u]; c=1 -> a2d.
__global__ void prep_wa_kernel(const float* __restrict__ W1, const float* __restrict__ a1s,
                               const float* __restrict__ a1d, const float* __restrict__ W2,
                               const float* __restrict__ a2s, const float* __restrict__ a2d,
                               float* __restrict__ Wa1, float* __restrict__ Wa2) {
    int t = blockIdx.x * blockDim.x + threadIdx.x;
    if (t < 128 * 8) {
        int f = t >> 3, c = t & 7, h = c & 3;
        const float* a = (c < 4) ? (a1s + h * 32) : (a1d + h * 32);
        const float* w = W1 + f * 128 + h * 32;
        float s = 0.f;
        #pragma unroll
        for (int u = 0; u < 32; ++u) s += w[u] * a[u];
        Wa1[f * 8 + c] = s;
    } else if (t < 128 * 8 + 128 * 2) {
        int q = t - 1024;
        int f = q >> 1, c = q & 1;
        const float* a = c ? a2d : a2s;
        const float* w = W2 + f * 32;
        float s = 0.f;
        #pragma unroll
        for (int u = 0; u < 32; ++u) s += w[u] * a[u];
        Wa2[f * 2 + c] = s;
    }
}

// ---------------- register-tiled GEMM + fused logit columns ----------------
// Hout[row][c] = sum_k X[row][k]*W[k][c] (f16 out); es/ed[row][*] = X·Wa (f32).
template<typename XT, int K, int COLS, int BM, int KC, int TM, int EX, int ESPLIT>
__global__ __launch_bounds__((BM / TM) * (COLS / 4))
void gemm_fused(const XT* __restrict__ X, const float* __restrict__ W,
                const float* __restrict__ Wa, __half* __restrict__ Hout,
                float* __restrict__ es, float* __restrict__ ed, int rows) {
    constexpr int TN = 4;
    constexpr int NCG = COLS / TN;
    constexpr int NRG = BM / TM;
    constexpr int NT = NCG * NRG;
    constexpr int XPAD = BM + 4;
    constexpr int PAIRS = (BM * EX + NT - 1) / NT;
    __shared__ float Xs[KC][XPAD];
    __shared__ float Ws[KC][COLS];
    __shared__ float WaS[KC][EX];
    const int tid = threadIdx.x;
    const int cg = tid % NCG;
    const int rg = tid / NCG;
    const int row0 = blockIdx.x * BM;
    float acc[TM][TN] = {};
    float exacc[PAIRS] = {};
    for (int k0 = 0; k0 < K; k0 += KC) {
        const float4* wsrc = (const float4*)(W + (size_t)k0 * COLS);
        float4* wdst = (float4*)&Ws[0][0];
        #pragma unroll
        for (int idx = tid; idx < KC * COLS / 4; idx += NT) wdst[idx] = wsrc[idx];
        for (int idx = tid; idx < KC * EX; idx += NT)
            ((float*)WaS)[idx] = Wa[k0 * EX + idx];
        constexpr int F4R = KC / 4;
        #pragma unroll
        for (int idx = tid; idx < BM * F4R; idx += NT) {
            int row = idx / F4R, k4 = idx % F4R;
            float4 v = Vec4Loader<XT>::load(X + (size_t)(row0 + row) * K + k0 + 4 * k4);
            Xs[4 * k4 + 0][row] = v.x;
            Xs[4 * k4 + 1][row] = v.y;
            Xs[4 * k4 + 2][row] = v.z;
            Xs[4 * k4 + 3][row] = v.w;
        }
        __syncthreads();
        #pragma unroll
        for (int k = 0; k < KC; ++k) {
            float wr[TN], xr[TM];
            *(float4*)wr = *(const float4*)&Ws[k][TN * cg];
            #pragma unroll
            for (int q = 0; q < TM / 4; ++q)
                *(float4*)&xr[4 * q] = *(const float4*)&Xs[k][TM * rg + 4 * q];
            #pragma unroll
            for (int i = 0; i < TM; ++i)
                #pragma unroll
                for (int j = 0; j < TN; ++j)
                    acc[i][j] += xr[i] * wr[j];
        }
        // fused logit dots: pair (row, c) flat-assigned over all threads (~6% extra)
        #pragma unroll
        for (int p = 0; p < PAIRS; ++p) {
            int pid = tid + p * NT;
            if (pid < BM * EX) {
                int r = pid / EX, c = pid % EX;
                float s = 0.f;
                #pragma unroll
                for (int k = 0; k < KC; ++k) s += Xs[k][r] * WaS[k][c];
                exacc[p] += s;
            }
        }
        __syncthreads();
    }
    #pragma unroll
    for (int i = 0; i < TM; ++i) {
        int row = row0 + TM * rg + i;
        if (row < rows) {
            __half2 h01 = __floats2half2_rn(acc[i][0], acc[i][1]);
            __half2 h23 = __floats2half2_rn(acc[i][2], acc[i][3]);
            uint2 pk;
            pk.x = *reinterpret_cast<unsigned int*>(&h01);
            pk.y = *reinterpret_cast<unsigned int*>(&h23);
            *reinterpret_cast<uint2*>(Hout + (size_t)row * COLS + TN * cg) = pk;
        }
    }
    #pragma unroll
    for (int p = 0; p < PAIRS; ++p) {
        int pid = tid + p * NT;
        if (pid < BM * EX) {
            int row = row0 + pid / EX, c = pid % EX;
            if (row < rows) {
                if (c < ESPLIT) es[(size_t)row * ESPLIT + c] = exacc[p];
                else            ed[(size_t)row * ESPLIT + (c - ESPLIT)] = exacc[p];
            }
        }
    }
}

// ---------------- CSR build ----------------
__global__ void deg_kernel(const int* __restrict__ edst, int* __restrict__ deg, int E) {
    int e = blockIdx.x * blockDim.x + threadIdx.x;
    if (e < E) atomicAdd(&deg[edst[e]], 1);
}

__global__ void scan_kernel(const int* __restrict__ deg, int* __restrict__ row_ptr, int N) {
    __shared__ int wsum[16];
    __shared__ int carryS;
    int tid = threadIdx.x;
    int wid = tid >> 6, lane = tid & 63;
    if (tid == 0) carryS = 0;
    __syncthreads();
    for (int base = 0; base < N; base += 1024) {
        int i = base + tid;
        int v = (i < N) ? deg[i] : 0;
        int x = v;
        #pragma unroll
        for (int off = 1; off < 64; off <<= 1) {
            int t = __shfl_up(x, off);
            if (lane >= off) x += t;
        }
        if (lane == 63) wsum[wid] = x;
        __syncthreads();
        if (wid == 0) {
            int s = (lane < 16) ? wsum[lane] : 0;
            #pragma unroll
            for (int off = 1; off < 16; off <<= 1) {
                int t = __shfl_up(s, off);
                if (lane >= off) s += t;
            }
            if (lane < 16) wsum[lane] = s;
        }
        __syncthreads();
        int wbase = carryS + (wid ? wsum[wid - 1] : 0);
        if (i < N) row_ptr[i] = wbase + x - v;
        int total = wsum[15];
        __syncthreads();
        if (tid == 0) carryS += total;
        __syncthreads();
    }
    if (threadIdx.x == 0) row_ptr[N] = carryS;
}

__global__ void scatter_kernel(const int* __restrict__ esrc, const int* __restrict__ edst,
                               const int* __restrict__ row_ptr, int* __restrict__ cursor,
                               int* __restrict__ col, int E) {
    int e = blockIdx.x * blockDim.x + threadIdx.x;
    if (e >= E) return;
    int d = edst[e];
    int pos = atomicAdd(&cursor[d], 1);
    col[row_ptr[d] + pos] = esrc[e];
}

// ---------------- layer-1 aggregation (batch->XCD swizzle, fma_mix inner) ---------
__global__ __launch_bounds__(512)
void agg1_kernel(const int* __restrict__ row_ptr, const int* __restrict__ col,
                 const float* __restrict__ es, const float* __restrict__ ed,
                 const __half* __restrict__ Hf, const float* __restrict__ bias,
                 __half* __restrict__ outH) {
    __shared__ float evS[8][64][4];
    __shared__ int colS[8][64];
    int blk = blockIdx.x;
    int b = blk & 7;                  // batch -> XCD
    int grp = blk >> 3;
    int w = threadIdx.x >> 6;
    int d = grp * 8 + w;
    int lane = threadIdx.x & 63;
    int eg = lane >> 4;
    int c8 = lane & 15;
    int head = c8 >> 2;
    int start = row_ptr[d], end = row_ptr[d + 1];
    size_t brow = (size_t)b * N_NODES;
    size_t drow = brow + d;
    float4 ed4 = ((const float4*)ed)[drow];
    float dx = 0.f, dy = 0.f, dz = 0.f, dw = 0.f;
    float acc[8] = {};
    const __half* hbase = Hf + (brow << 7) + (c8 << 3);
    for (int i0 = start; i0 < end; i0 += 64) {
        int nch = end - i0; if (nch > 64) nch = 64;
        WAVE_FENCE();   // WAR
        if (lane < nch) {
            int s = col[i0 + lane];
            colS[w][lane] = s;
            float4 e4 = ((const float4*)es)[brow + s];
            float l, a0, a1, a2, a3;
            l = e4.x + ed4.x; l = l > 0.f ? l : 0.2f * l; a0 = __expf(l); dx += a0;
            l = e4.y + ed4.y; l = l > 0.f ? l : 0.2f * l; a1 = __expf(l); dy += a1;
            l = e4.z + ed4.z; l = l > 0.f ? l : 0.2f * l; a2 = __expf(l); dz += a2;
            l = e4.w + ed4.w; l = l > 0.f ? l : 0.2f * l; a3 = __expf(l); dw += a3;
            *(float4*)&evS[w][lane][0] = make_float4(a0, a1, a2, a3);
        }
        WAVE_FENCE();   // RAW
        for (int t = 0; t < nch; t += 4) {
            int myt = t + eg;
            int tt = myt < nch ? myt : 0;
            float a = evS[w][tt][head];
            if (myt >= nch) a = 0.f;
            int s = colS[w][tt];
            float4 raw = *(const float4*)(hbase + ((size_t)s << 7));
            const unsigned* u = (const unsigned*)&raw;
            #pragma unroll
            for (int j = 0; j < 4; ++j) {
                FMA_MIX_LO(acc[2 * j],     u[j], a);
                FMA_MIX_HI(acc[2 * j + 1], u[j], a);
            }
        }
    }
    #pragma unroll
    for (int off = 32; off; off >>= 1) {
        dx += __shfl_xor(dx, off);
        dy += __shfl_xor(dy, off);
        dz += __shfl_xor(dz, off);
        dw += __shfl_xor(dw, off);
    }
    float ix = 1.f / (dx + 1e-9f);
    float iy = 1.f / (dy + 1e-9f);
    float iz = 1.f / (dz + 1e-9f);
    float iw = 1.f / (dw + 1e-9f);
    float inv = (head & 2) ? ((head & 1) ? iw : iz) : ((head & 1) ? iy : ix);
    #pragma unroll
    for (int j = 0; j < 8; ++j) {
        acc[j] += __shfl_xor(acc[j], 16);
        acc[j] += __shfl_xor(acc[j], 32);
    }
    if (eg == 0) {
        float4 b0 = *(const float4*)(bias + 8 * c8);
        float4 b1 = *(const float4*)(bias + 8 * c8 + 4);
        float vals[8];
        vals[0] = fmaxf(acc[0] * inv + b0.x, 0.f);
        vals[1] = fmaxf(acc[1] * inv + b0.y, 0.f);
        vals[2] = fmaxf(acc[2] * inv + b0.z, 0.f);
        vals[3] = fmaxf(acc[3] * inv + b0.w, 0.f);
        vals[4] = fmaxf(acc[4] * inv + b1.x, 0.f);
        vals[5] = fmaxf(acc[5] * inv + b1.y, 0.f);
        vals[6] = fmaxf(acc[6] * inv + b1.z, 0.f);
        vals[7] = fmaxf(acc[7] * inv + b1.w, 0.f);
        __half2 o[4];
        #pragma unroll
        for (int j = 0; j < 4; ++j) o[j] = __floats2half2_rn(vals[2 * j], vals[2 * j + 1]);
        *(float4*)(outH + drow * 128 + c8 * 8) = *(float4*)o;
    }
}

// ---------------- layer-2 aggregation (same swizzle, fma_mix inner) ---------------
__global__ __launch_bounds__(512)
void agg2_kernel(const int* __restrict__ row_ptr, const int* __restrict__ col,
                 const float* __restrict__ es, const float* __restrict__ ed,
                 const __half* __restrict__ Hf, const float* __restrict__ bias,
                 float* __restrict__ outF) {
    __shared__ float evS[8][64];
    __shared__ int colS[8][64];
    int blk = blockIdx.x;
    int b = blk & 7;
    int grp = blk >> 3;
    int w = threadIdx.x >> 6;
    int d = grp * 8 + w;
    int lane = threadIdx.x & 63;
    int eg = lane >> 2;
    int c8 = lane & 3;
    int start = row_ptr[d], end = row_ptr[d + 1];
    size_t brow = (size_t)b * N_NODES;
    size_t drow = brow + d;
    float edv = ed[drow];
    float den = 0.f;
    float acc[8] = {};
    const __half* hbase = Hf + (brow << 5) + (c8 << 3);
    for (int i0 = start; i0 < end; i0 += 64) {
        int nch = end - i0; if (nch > 64) nch = 64;
        WAVE_FENCE();
        if (lane < nch) {
            int s = col[i0 + lane];
            colS[w][lane] = s;
            float l = es[brow + s] + edv;
            l = l > 0.f ? l : 0.2f * l;
            float ev = __expf(l);
            den += ev;
            evS[w][lane] = ev;
        }
        WAVE_FENCE();
        for (int t = 0; t < nch; t += 16) {
            int myt = t + eg;
            int tt = myt < nch ? myt : 0;
            float a = evS[w][tt];
            if (myt >= nch) a = 0.f;
            int s = colS[w][tt];
            float4 raw = *(const float4*)(hbase + ((size_t)s << 5));
            const unsigned* u = (const unsigned*)&raw;
            #pragma unroll
            for (int j = 0; j < 4; ++j) {
                FMA_MIX_LO(acc[2 * j],     u[j], a);
                FMA_MIX_HI(acc[2 * j + 1], u[j], a);
            }
        }
    }
    #pragma unroll
    for (int off = 32; off; off >>= 1) den += __shfl_xor(den, off);
    float inv = 1.f / (den + 1e-9f);
    #pragma unroll
    for (int j = 0; j < 8; ++j) {
        acc[j] += __shfl_xor(acc[j], 4);
        acc[j] += __shfl_xor(acc[j], 8);
        acc[j] += __shfl_xor(acc[j], 16);
        acc[j] += __shfl_xor(acc[j], 32);
    }
    if (eg == 0) {
        float4 b0 = *(const float4*)(bias + 8 * c8);
        float4 b1 = *(const float4*)(bias + 8 * c8 + 4);
        float4 o0, o1;
        o0.x = acc[0] * inv + b0.x;
        o0.y = acc[1] * inv + b0.y;
        o0.z = acc[2] * inv + b0.z;
        o0.w = acc[3] * inv + b0.w;
        o1.x = acc[4] * inv + b1.x;
        o1.y = acc[5] * inv + b1.y;
        o1.z = acc[6] * inv + b1.z;
        o1.w = acc[7] * inv + b1.w;
        float* op = outF + drow * 32 + 8 * c8;
        *(float4*)op = o0;
        *(float4*)(op + 4) = o1;
    }
}

extern "C" void kernel_launch(void* const* d_in, const int* in_sizes, int n_in,
                              void* d_out, int out_size, void* d_ws, size_t ws_size,
                              hipStream_t stream) {
    const float* x    = (const float*)d_in[0];
    const int*   esrc = (const int*)d_in[1];
    const int*   edst = (const int*)d_in[2];
    const float* W1   = (const float*)d_in[3];
    const float* a1s  = (const float*)d_in[4];
    const float* a1d  = (const float*)d_in[5];
    const float* b1   = (const float*)d_in[6];
    const float* W2   = (const float*)d_in[7];
    const float* a2s  = (const float*)d_in[8];
    const float* a2d  = (const float*)d_in[9];
    const float* b2   = (const float*)d_in[10];
    float* out = (float*)d_out;
    const int E = in_sizes[1];
    const int rows = BATCH * N_NODES;  // 80000

    // workspace layout
    float* wsf = (float*)d_ws;
    __half* h1h   = (__half*)wsf;                       // rows*128 halfs
    float*  e1s   = wsf + (size_t)rows * 64;            // rows*4
    float*  e1d   = e1s + (size_t)rows * 4;             // rows*4
    __half* out1h = (__half*)(e1d + (size_t)rows * 4);  // rows*128 halfs
    int* deg      = (int*)((float*)out1h + (size_t)rows * 64);  // N
    int* cursor   = deg + N_NODES;                      // N
    int* row_ptr  = cursor + N_NODES;                   // N+1
    int* colIdx   = row_ptr + N_NODES + 1;              // E
    float* Wa1    = (float*)(colIdx + E);               // 128*8
    float* Wa2    = Wa1 + 128 * 8;                      // 128*2
    // layer 2 reuse
    __half* h2h = h1h;
    float*  e2s = e1s;
    float*  e2d = e1s + rows;

    const int TPB = 256;

    // ---------- prep + CSR build ----------
    hipMemsetAsync(deg, 0, N_NODES * sizeof(int), stream);
    hipMemsetAsync(cursor, 0, N_NODES * sizeof(int), stream);
    prep_wa_kernel<<<5, 256, 0, stream>>>(W1, a1s, a1d, W2, a2s, a2d, Wa1, Wa2);
    deg_kernel<<<(E + TPB - 1) / TPB, TPB, 0, stream>>>(edst, deg, E);
    scan_kernel<<<1, 1024, 0, stream>>>(deg, row_ptr, N_NODES);
    scatter_kernel<<<(E + TPB - 1) / TPB, TPB, 0, stream>>>(esrc, edst, row_ptr, cursor, colIdx, E);

    // ---------- layer 1 ----------
    gemm_fused<float, FIN, 128, 64, 32, 8, 8, 4><<<rows / 64, 256, 0, stream>>>(
        x, W1, Wa1, h1h, e1s, e1d, rows);
    agg1_kernel<<<(N_NODES / 8) * BATCH, 512, 0, stream>>>(row_ptr, colIdx, e1s, e1d, h1h, b1, out1h);

    // ---------- layer 2 ----------
    gemm_fused<__half, 128, UNITS, 128, 32, 4, 2, 1><<<rows / 128, 256, 0, stream>>>(
        out1h, W2, Wa2, h2h, e2s, e2d, rows);
    agg2_kernel<<<(N_NODES / 8) * BATCH, 512, 0, stream>>>(row_ptr, colIdx, e2s, e2d, h2h, b2, out);
}

// Round 9
// 234.623 us; speedup vs baseline: 1.3115x; 1.3115x over previous
//
#include <hip/hip_runtime.h>
#include <hip/hip_fp16.h>

#define N_NODES 10000
#define BATCH 8
#define FIN 128
#define UNITS 32
#define NH1 4

#define WAVE_FENCE() asm volatile("s_waitcnt lgkmcnt(0)" ::: "memory")

// f16(lo/hi of u32) * f32 + f32 -> f32, one VOP3P instruction (no separate cvt)
#define FMA_MIX_LO(acc, u, a) \
    asm("v_fma_mix_f32 %0, %1, %2, %0 op_sel:[0,0,0] op_sel_hi:[1,0,0]" \
        : "+v"(acc) : "v"(u), "v"(a))
#define FMA_MIX_HI(acc, u, a) \
    asm("v_fma_mix_f32 %0, %1, %2, %0 op_sel:[1,0,0] op_sel_hi:[1,0,0]" \
        : "+v"(acc) : "v"(u), "v"(a))

// ---------------- vec4 loader (f32 or f16 source) ----------------
template<typename T> struct Vec4Loader;
template<> struct Vec4Loader<float> {
    static __device__ inline float4 load(const float* p) { return *(const float4*)p; }
};
template<> struct Vec4Loader<__half> {
    static __device__ inline float4 load(const __half* p) {
        const __half2* p2 = (const __half2*)p;
        float2 a = __half22float2(p2[0]);
        float2 b = __half22float2(p2[1]);
        return make_float4(a.x, a.y, b.x, b.y);
    }
};

// ---------------- register-tiled GEMM: Hout[row][c] = sum_k X[row][k]*W[k][c] ------
// 4x4 outputs/thread, KC-chunked, X transposed in LDS. f16 output. VGPR ~64.
template<typename XT, int K, int COLS, int BM, int KC>
__global__ __launch_bounds__((BM / 4) * (COLS / 4))
void gemm_tiled_h(const XT* __restrict__ X, const float* __restrict__ W,
                  __half* __restrict__ Hout, int rows) {
    constexpr int TM = 4, TN = 4;
    constexpr int NCG = COLS / TN;
    constexpr int NRG = BM / TM;
    constexpr int NT = NCG * NRG;
    constexpr int XPAD = BM + 4;
    __shared__ float Xs[KC][XPAD];
    __shared__ float Ws[KC][COLS];
    const int tid = threadIdx.x;
    const int cg = tid % NCG;
    const int rg = tid / NCG;
    const int row0 = blockIdx.x * BM;
    float acc[TM][TN] = {};
    for (int k0 = 0; k0 < K; k0 += KC) {
        const float4* wsrc = (const float4*)(W + (size_t)k0 * COLS);
        float4* wdst = (float4*)&Ws[0][0];
        #pragma unroll
        for (int idx = tid; idx < KC * COLS / 4; idx += NT) wdst[idx] = wsrc[idx];
        constexpr int F4R = KC / 4;
        #pragma unroll
        for (int idx = tid; idx < BM * F4R; idx += NT) {
            int row = idx / F4R, k4 = idx % F4R;
            float4 v = Vec4Loader<XT>::load(X + (size_t)(row0 + row) * K + k0 + 4 * k4);
            Xs[4 * k4 + 0][row] = v.x;
            Xs[4 * k4 + 1][row] = v.y;
            Xs[4 * k4 + 2][row] = v.z;
            Xs[4 * k4 + 3][row] = v.w;
        }
        __syncthreads();
        #pragma unroll
        for (int k = 0; k < KC; ++k) {
            float wr[TN], xr[TM];
            *(float4*)wr = *(const float4*)&Ws[k][TN * cg];
            *(float4*)xr = *(const float4*)&Xs[k][TM * rg];
            #pragma unroll
            for (int i = 0; i < TM; ++i)
                #pragma unroll
                for (int j = 0; j < TN; ++j)
                    acc[i][j] += xr[i] * wr[j];
        }
        __syncthreads();
    }
    #pragma unroll
    for (int i = 0; i < TM; ++i) {
        int row = row0 + TM * rg + i;
        if (row < rows) {
            __half2 h01 = __floats2half2_rn(acc[i][0], acc[i][1]);
            __half2 h23 = __floats2half2_rn(acc[i][2], acc[i][3]);
            uint2 pk;
            pk.x = *reinterpret_cast<unsigned int*>(&h01);
            pk.y = *reinterpret_cast<unsigned int*>(&h23);
            *reinterpret_cast<uint2*>(Hout + (size_t)row * COLS + TN * cg) = pk;
        }
    }
}

// ---------------- attention logits from f16 features ----------------
template<int H>
__global__ void att_logits_h(const __half* __restrict__ Hf,
                             const float* __restrict__ a_src,
                             const float* __restrict__ a_dst,
                             float* __restrict__ es, float* __restrict__ ed,
                             int rows) {
    int t = blockIdx.x * blockDim.x + threadIdx.x;
    if (t >= rows * H) return;
    int row = t / H, h = t % H;
    const __half2* hv = (const __half2*)(Hf + (size_t)row * (H * UNITS) + h * UNITS);
    const float* as = a_src + h * UNITS;
    const float* ad = a_dst + h * UNITS;
    float s = 0.f, d = 0.f;
    #pragma unroll
    for (int i = 0; i < UNITS / 2; ++i) {
        float2 xv = __half22float2(hv[i]);
        s += xv.x * as[2 * i] + xv.y * as[2 * i + 1];
        d += xv.x * ad[2 * i] + xv.y * ad[2 * i + 1];
    }
    es[t] = s;
    ed[t] = d;
}

// ---------------- CSR build ----------------
__global__ void deg_kernel(const int* __restrict__ edst, int* __restrict__ deg, int E) {
    int e = blockIdx.x * blockDim.x + threadIdx.x;
    if (e < E) atomicAdd(&deg[edst[e]], 1);
}

__global__ void scan_kernel(const int* __restrict__ deg, int* __restrict__ row_ptr, int N) {
    __shared__ int wsum[16];
    __shared__ int carryS;
    int tid = threadIdx.x;
    int wid = tid >> 6, lane = tid & 63;
    if (tid == 0) carryS = 0;
    __syncthreads();
    for (int base = 0; base < N; base += 1024) {
        int i = base + tid;
        int v = (i < N) ? deg[i] : 0;
        int x = v;
        #pragma unroll
        for (int off = 1; off < 64; off <<= 1) {
            int t = __shfl_up(x, off);
            if (lane >= off) x += t;
        }
        if (lane == 63) wsum[wid] = x;
        __syncthreads();
        if (wid == 0) {
            int s = (lane < 16) ? wsum[lane] : 0;
            #pragma unroll
            for (int off = 1; off < 16; off <<= 1) {
                int t = __shfl_up(s, off);
                if (lane >= off) s += t;
            }
            if (lane < 16) wsum[lane] = s;
        }
        __syncthreads();
        int wbase = carryS + (wid ? wsum[wid - 1] : 0);
        if (i < N) row_ptr[i] = wbase + x - v;
        int total = wsum[15];
        __syncthreads();
        if (tid == 0) carryS += total;
        __syncthreads();
    }
    if (threadIdx.x == 0) row_ptr[N] = carryS;
}

__global__ void scatter_kernel(const int* __restrict__ esrc, const int* __restrict__ edst,
                               const int* __restrict__ row_ptr, int* __restrict__ cursor,
                               int* __restrict__ col, int E) {
    int e = blockIdx.x * blockDim.x + threadIdx.x;
    if (e >= E) return;
    int d = edst[e];
    int pos = atomicAdd(&cursor[d], 1);
    col[row_ptr[d] + pos] = esrc[e];
}

// ---------------- layer-1 aggregation (batch->XCD swizzle, fma_mix inner) ---------
__global__ __launch_bounds__(512)
void agg1_kernel(const int* __restrict__ row_ptr, const int* __restrict__ col,
                 const float* __restrict__ es, const float* __restrict__ ed,
                 const __half* __restrict__ Hf, const float* __restrict__ bias,
                 __half* __restrict__ outH) {
    __shared__ float evS[8][64][4];
    __shared__ int colS[8][64];
    int blk = blockIdx.x;
    int b = blk & 7;                  // batch -> XCD
    int grp = blk >> 3;
    int w = threadIdx.x >> 6;
    int d = grp * 8 + w;
    int lane = threadIdx.x & 63;
    int eg = lane >> 4;
    int c8 = lane & 15;
    int head = c8 >> 2;
    int start = row_ptr[d], end = row_ptr[d + 1];
    size_t brow = (size_t)b * N_NODES;
    size_t drow = brow + d;
    float4 ed4 = ((const float4*)ed)[drow];
    float dx = 0.f, dy = 0.f, dz = 0.f, dw = 0.f;
    float acc[8] = {};
    const __half* hbase = Hf + (brow << 7) + (c8 << 3);
    for (int i0 = start; i0 < end; i0 += 64) {
        int nch = end - i0; if (nch > 64) nch = 64;
        WAVE_FENCE();   // WAR
        if (lane < nch) {
            int s = col[i0 + lane];
            colS[w][lane] = s;
            float4 e4 = ((const float4*)es)[brow + s];
            float l, a0, a1, a2, a3;
            l = e4.x + ed4.x; l = l > 0.f ? l : 0.2f * l; a0 = __expf(l); dx += a0;
            l = e4.y + ed4.y; l = l > 0.f ? l : 0.2f * l; a1 = __expf(l); dy += a1;
            l = e4.z + ed4.z; l = l > 0.f ? l : 0.2f * l; a2 = __expf(l); dz += a2;
            l = e4.w + ed4.w; l = l > 0.f ? l : 0.2f * l; a3 = __expf(l); dw += a3;
            *(float4*)&evS[w][lane][0] = make_float4(a0, a1, a2, a3);
        }
        WAVE_FENCE();   // RAW
        for (int t = 0; t < nch; t += 4) {
            int myt = t + eg;
            int tt = myt < nch ? myt : 0;
            float a = evS[w][tt][head];
            if (myt >= nch) a = 0.f;
            int s = colS[w][tt];
            float4 raw = *(const float4*)(hbase + ((size_t)s << 7));
            const unsigned* u = (const unsigned*)&raw;
            #pragma unroll
            for (int j = 0; j < 4; ++j) {
                FMA_MIX_LO(acc[2 * j],     u[j], a);
                FMA_MIX_HI(acc[2 * j + 1], u[j], a);
            }
        }
    }
    #pragma unroll
    for (int off = 32; off; off >>= 1) {
        dx += __shfl_xor(dx, off);
        dy += __shfl_xor(dy, off);
        dz += __shfl_xor(dz, off);
        dw += __shfl_xor(dw, off);
    }
    float ix = 1.f / (dx + 1e-9f);
    float iy = 1.f / (dy + 1e-9f);
    float iz = 1.f / (dz + 1e-9f);
    float iw = 1.f / (dw + 1e-9f);
    float inv = (head & 2) ? ((head & 1) ? iw : iz) : ((head & 1) ? iy : ix);
    #pragma unroll
    for (int j = 0; j < 8; ++j) {
        acc[j] += __shfl_xor(acc[j], 16);
        acc[j] += __shfl_xor(acc[j], 32);
    }
    if (eg == 0) {
        float4 b0 = *(const float4*)(bias + 8 * c8);
        float4 b1 = *(const float4*)(bias + 8 * c8 + 4);
        float vals[8];
        vals[0] = fmaxf(acc[0] * inv + b0.x, 0.f);
        vals[1] = fmaxf(acc[1] * inv + b0.y, 0.f);
        vals[2] = fmaxf(acc[2] * inv + b0.z, 0.f);
        vals[3] = fmaxf(acc[3] * inv + b0.w, 0.f);
        vals[4] = fmaxf(acc[4] * inv + b1.x, 0.f);
        vals[5] = fmaxf(acc[5] * inv + b1.y, 0.f);
        vals[6] = fmaxf(acc[6] * inv + b1.z, 0.f);
        vals[7] = fmaxf(acc[7] * inv + b1.w, 0.f);
        __half2 o[4];
        #pragma unroll
        for (int j = 0; j < 4; ++j) o[j] = __floats2half2_rn(vals[2 * j], vals[2 * j + 1]);
        *(float4*)(outH + drow * 128 + c8 * 8) = *(float4*)o;
    }
}

// ---------------- layer-2 aggregation (same swizzle, fma_mix inner) ---------------
__global__ __launch_bounds__(512)
void agg2_kernel(const int* __restrict__ row_ptr, const int* __restrict__ col,
                 const float* __restrict__ es, const float* __restrict__ ed,
                 const __half* __restrict__ Hf, const float* __restrict__ bias,
                 float* __restrict__ outF) {
    __shared__ float evS[8][64];
    __shared__ int colS[8][64];
    int blk = blockIdx.x;
    int b = blk & 7;
    int grp = blk >> 3;
    int w = threadIdx.x >> 6;
    int d = grp * 8 + w;
    int lane = threadIdx.x & 63;
    int eg = lane >> 2;
    int c8 = lane & 3;
    int start = row_ptr[d], end = row_ptr[d + 1];
    size_t brow = (size_t)b * N_NODES;
    size_t drow = brow + d;
    float edv = ed[drow];
    float den = 0.f;
    float acc[8] = {};
    const __half* hbase = Hf + (brow << 5) + (c8 << 3);
    for (int i0 = start; i0 < end; i0 += 64) {
        int nch = end - i0; if (nch > 64) nch = 64;
        WAVE_FENCE();
        if (lane < nch) {
            int s = col[i0 + lane];
            colS[w][lane] = s;
            float l = es[brow + s] + edv;
            l = l > 0.f ? l : 0.2f * l;
            float ev = __expf(l);
            den += ev;
            evS[w][lane] = ev;
        }
        WAVE_FENCE();
        for (int t = 0; t < nch; t += 16) {
            int myt = t + eg;
            int tt = myt < nch ? myt : 0;
            float a = evS[w][tt];
            if (myt >= nch) a = 0.f;
            int s = colS[w][tt];
            float4 raw = *(const float4*)(hbase + ((size_t)s << 5));
            const unsigned* u = (const unsigned*)&raw;
            #pragma unroll
            for (int j = 0; j < 4; ++j) {
                FMA_MIX_LO(acc[2 * j],     u[j], a);
                FMA_MIX_HI(acc[2 * j + 1], u[j], a);
            }
        }
    }
    #pragma unroll
    for (int off = 32; off; off >>= 1) den += __shfl_xor(den, off);
    float inv = 1.f / (den + 1e-9f);
    #pragma unroll
    for (int j = 0; j < 8; ++j) {
        acc[j] += __shfl_xor(acc[j], 4);
        acc[j] += __shfl_xor(acc[j], 8);
        acc[j] += __shfl_xor(acc[j], 16);
        acc[j] += __shfl_xor(acc[j], 32);
    }
    if (eg == 0) {
        float4 b0 = *(const float4*)(bias + 8 * c8);
        float4 b1 = *(const float4*)(bias + 8 * c8 + 4);
        float4 o0, o1;
        o0.x = acc[0] * inv + b0.x;
        o0.y = acc[1] * inv + b0.y;
        o0.z = acc[2] * inv + b0.z;
        o0.w = acc[3] * inv + b0.w;
        o1.x = acc[4] * inv + b1.x;
        o1.y = acc[5] * inv + b1.y;
        o1.z = acc[6] * inv + b1.z;
        o1.w = acc[7] * inv + b1.w;
        float* op = outF + drow * 32 + 8 * c8;
        *(float4*)op = o0;
        *(float4*)(op + 4) = o1;
    }
}

extern "C" void kernel_launch(void* const* d_in, const int* in_sizes, int n_in,
                              void* d_out, int out_size, void* d_ws, size_t ws_size,
                              hipStream_t stream) {
    const float* x    = (const float*)d_in[0];
    const int*   esrc = (const int*)d_in[1];
    const int*   edst = (const int*)d_in[2];
    const float* W1   = (const float*)d_in[3];
    const float* a1s  = (const float*)d_in[4];
    const float* a1d  = (const float*)d_in[5];
    const float* b1   = (const float*)d_in[6];
    const float* W2   = (const float*)d_in[7];
    const float* a2s  = (const float*)d_in[8];
    const float* a2d  = (const float*)d_in[9];
    const float* b2   = (const float*)d_in[10];
    float* out = (float*)d_out;
    const int E = in_sizes[1];
    const int rows = BATCH * N_NODES;  // 80000

    // workspace layout
    float* wsf = (float*)d_ws;
    __half* h1h   = (__half*)wsf;                       // rows*128 halfs
    float*  e1s   = wsf + (size_t)rows * 64;            // rows*4
    float*  e1d   = e1s + (size_t)rows * 4;             // rows*4
    __half* out1h = (__half*)(e1d + (size_t)rows * 4);  // rows*128 halfs
    int* deg      = (int*)((float*)out1h + (size_t)rows * 64);  // N
    int* cursor   = deg + N_NODES;                      // N
    int* row_ptr  = cursor + N_NODES;                   // N+1
    int* colIdx   = row_ptr + N_NODES + 1;              // E
    // layer 2 reuse
    __half* h2h = h1h;
    float*  e2s = e1s;
    float*  e2d = e1s + rows;

    const int TPB = 256;

    // ---------- CSR build (shared by both layers) ----------
    hipMemsetAsync(deg, 0, N_NODES * sizeof(int), stream);
    hipMemsetAsync(cursor, 0, N_NODES * sizeof(int), stream);
    deg_kernel<<<(E + TPB - 1) / TPB, TPB, 0, stream>>>(edst, deg, E);
    scan_kernel<<<1, 1024, 0, stream>>>(deg, row_ptr, N_NODES);
    scatter_kernel<<<(E + TPB - 1) / TPB, TPB, 0, stream>>>(esrc, edst, row_ptr, cursor, colIdx, E);

    // ---------- layer 1 ----------
    gemm_tiled_h<float, FIN, 128, 32, 32><<<rows / 32, 256, 0, stream>>>(x, W1, h1h, rows);
    att_logits_h<NH1><<<(rows * NH1 + TPB - 1) / TPB, TPB, 0, stream>>>(
        h1h, a1s, a1d, e1s, e1d, rows);
    agg1_kernel<<<(N_NODES / 8) * BATCH, 512, 0, stream>>>(row_ptr, colIdx, e1s, e1d, h1h, b1, out1h);

    // ---------- layer 2 ----------
    gemm_tiled_h<__half, 128, UNITS, 128, 32><<<rows / 128, 256, 0, stream>>>(out1h, W2, h2h, rows);
    att_logits_h<1><<<(rows + TPB - 1) / TPB, TPB, 0, stream>>>(
        h2h, a2s, a2d, e2s, e2d, rows);
    agg2_kernel<<<(N_NODES / 8) * BATCH, 512, 0, stream>>>(row_ptr, colIdx, e2s, e2d, h2h, b2, out);
}

// Round 10
// 213.450 us; speedup vs baseline: 1.4416x; 1.0992x over previous
//
#include <hip/hip_runtime.h>
#include <hip/hip_fp16.h>

#define N_NODES 10000
#define BATCH 8
#define FIN 128
#define UNITS 32
#define NH1 4

#define WAVE_FENCE() asm volatile("s_waitcnt lgkmcnt(0)" ::: "memory")

// f16(lo/hi of u32) * f32 + f32 -> f32, one VOP3P instruction
#define FMA_MIX_LO(acc, u, a) \
    asm("v_fma_mix_f32 %0, %1, %2, %0 op_sel:[0,0,0] op_sel_hi:[1,0,0]" \
        : "+v"(acc) : "v"(u), "v"(a))
#define FMA_MIX_HI(acc, u, a) \
    asm("v_fma_mix_f32 %0, %1, %2, %0 op_sel:[1,0,0] op_sel_hi:[1,0,0]" \
        : "+v"(acc) : "v"(u), "v"(a))

// ---------------- vec4 loader (f32 or f16 source) ----------------
template<typename T> struct Vec4Loader;
template<> struct Vec4Loader<float> {
    static __device__ inline float4 load(const float* p) { return *(const float4*)p; }
};
template<> struct Vec4Loader<__half> {
    static __device__ inline float4 load(const __half* p) {
        const __half2* p2 = (const __half2*)p;
        float2 a = __half22float2(p2[0]);
        float2 b = __half22float2(p2[1]);
        return make_float4(a.x, a.y, b.x, b.y);
    }
};

// ---------------- register-tiled GEMM + register-space logits epilogue ------------
// Hout[row][c] = sum_k X[row][k]*W[k][c] (f16). After the K loop, each thread's
// acc[i][0..3] covers 4 cols of head h=cg>>3; es/ed reduce over the 8 threads
// (q=cg&7) sharing that head via shfl_xor 1/2/4. No main-loop pressure.
template<typename XT, int K, int COLS, int BM, int KC, int H>
__global__ __launch_bounds__((BM / 4) * (COLS / 4))
void gemm_att(const XT* __restrict__ X, const float* __restrict__ W,
              const float* __restrict__ a_src, const float* __restrict__ a_dst,
              __half* __restrict__ Hout, float* __restrict__ es,
              float* __restrict__ ed, int rows) {
    constexpr int TM = 4, TN = 4;
    constexpr int NCG = COLS / TN;
    constexpr int NRG = BM / TM;
    constexpr int NT = NCG * NRG;
    constexpr int XPAD = BM + 4;
    __shared__ float Xs[KC][XPAD];
    __shared__ float Ws[KC][COLS];
    const int tid = threadIdx.x;
    const int cg = tid % NCG;
    const int rg = tid / NCG;
    const int row0 = blockIdx.x * BM;
    float acc[TM][TN] = {};
    for (int k0 = 0; k0 < K; k0 += KC) {
        const float4* wsrc = (const float4*)(W + (size_t)k0 * COLS);
        float4* wdst = (float4*)&Ws[0][0];
        #pragma unroll
        for (int idx = tid; idx < KC * COLS / 4; idx += NT) wdst[idx] = wsrc[idx];
        constexpr int F4R = KC / 4;
        #pragma unroll
        for (int idx = tid; idx < BM * F4R; idx += NT) {
            int row = idx / F4R, k4 = idx % F4R;
            float4 v = Vec4Loader<XT>::load(X + (size_t)(row0 + row) * K + k0 + 4 * k4);
            Xs[4 * k4 + 0][row] = v.x;
            Xs[4 * k4 + 1][row] = v.y;
            Xs[4 * k4 + 2][row] = v.z;
            Xs[4 * k4 + 3][row] = v.w;
        }
        __syncthreads();
        #pragma unroll
        for (int k = 0; k < KC; ++k) {
            float wr[TN], xr[TM];
            *(float4*)wr = *(const float4*)&Ws[k][TN * cg];
            *(float4*)xr = *(const float4*)&Xs[k][TM * rg];
            #pragma unroll
            for (int i = 0; i < TM; ++i)
                #pragma unroll
                for (int j = 0; j < TN; ++j)
                    acc[i][j] += xr[i] * wr[j];
        }
        __syncthreads();
    }
    // H-matrix write (f16)
    #pragma unroll
    for (int i = 0; i < TM; ++i) {
        int row = row0 + TM * rg + i;
        if (row < rows) {
            __half2 h01 = __floats2half2_rn(acc[i][0], acc[i][1]);
            __half2 h23 = __floats2half2_rn(acc[i][2], acc[i][3]);
            uint2 pk;
            pk.x = *reinterpret_cast<unsigned int*>(&h01);
            pk.y = *reinterpret_cast<unsigned int*>(&h23);
            *reinterpret_cast<uint2*>(Hout + (size_t)row * COLS + TN * cg) = pk;
        }
    }
    // fused logits: thread's cols = 32*h + 4*q + j
    int q = cg & 7, h = cg >> 3;
    float4 as4 = *(const float4*)(a_src + h * UNITS + 4 * q);
    float4 ad4 = *(const float4*)(a_dst + h * UNITS + 4 * q);
    #pragma unroll
    for (int i = 0; i < TM; ++i) {
        float esp = acc[i][0] * as4.x + acc[i][1] * as4.y
                  + acc[i][2] * as4.z + acc[i][3] * as4.w;
        float edp = acc[i][0] * ad4.x + acc[i][1] * ad4.y
                  + acc[i][2] * ad4.z + acc[i][3] * ad4.w;
        esp += __shfl_xor(esp, 1); esp += __shfl_xor(esp, 2); esp += __shfl_xor(esp, 4);
        edp += __shfl_xor(edp, 1); edp += __shfl_xor(edp, 2); edp += __shfl_xor(edp, 4);
        int row = row0 + TM * rg + i;
        if (q == 0 && row < rows) {
            es[(size_t)row * H + h] = esp;
            ed[(size_t)row * H + h] = edp;
        }
    }
}

// ---------------- CSR build ----------------
__global__ void deg_kernel(const int* __restrict__ edst, int* __restrict__ deg, int E) {
    int e = blockIdx.x * blockDim.x + threadIdx.x;
    if (e < E) atomicAdd(&deg[edst[e]], 1);
}

__global__ void scan_kernel(const int* __restrict__ deg, int* __restrict__ row_ptr, int N) {
    __shared__ int wsum[16];
    __shared__ int carryS;
    int tid = threadIdx.x;
    int wid = tid >> 6, lane = tid & 63;
    if (tid == 0) carryS = 0;
    __syncthreads();
    for (int base = 0; base < N; base += 1024) {
        int i = base + tid;
        int v = (i < N) ? deg[i] : 0;
        int x = v;
        #pragma unroll
        for (int off = 1; off < 64; off <<= 1) {
            int t = __shfl_up(x, off);
            if (lane >= off) x += t;
        }
        if (lane == 63) wsum[wid] = x;
        __syncthreads();
        if (wid == 0) {
            int s = (lane < 16) ? wsum[lane] : 0;
            #pragma unroll
            for (int off = 1; off < 16; off <<= 1) {
                int t = __shfl_up(s, off);
                if (lane >= off) s += t;
            }
            if (lane < 16) wsum[lane] = s;
        }
        __syncthreads();
        int wbase = carryS + (wid ? wsum[wid - 1] : 0);
        if (i < N) row_ptr[i] = wbase + x - v;
        int total = wsum[15];
        __syncthreads();
        if (tid == 0) carryS += total;
        __syncthreads();
    }
    if (threadIdx.x == 0) row_ptr[N] = carryS;
}

__global__ void scatter_kernel(const int* __restrict__ esrc, const int* __restrict__ edst,
                               const int* __restrict__ row_ptr, int* __restrict__ cursor,
                               int* __restrict__ col, int E) {
    int e = blockIdx.x * blockDim.x + threadIdx.x;
    if (e >= E) return;
    int d = edst[e];
    int pos = atomicAdd(&cursor[d], 1);
    col[row_ptr[d] + pos] = esrc[e];
}

// ---------------- layer-1 aggregation (guard-free main loop, 2-edge unroll) -------
__global__ __launch_bounds__(512)
void agg1_kernel(const int* __restrict__ row_ptr, const int* __restrict__ col,
                 const float* __restrict__ es, const float* __restrict__ ed,
                 const __half* __restrict__ Hf, const float* __restrict__ bias,
                 __half* __restrict__ outH) {
    __shared__ float evS[8][64][4];
    __shared__ int colS[8][64];
    int blk = blockIdx.x;
    int b = blk & 7;                  // batch -> XCD
    int grp = blk >> 3;
    int w = threadIdx.x >> 6;
    int d = grp * 8 + w;
    int lane = threadIdx.x & 63;
    int eg = lane >> 4;
    int c8 = lane & 15;
    int head = c8 >> 2;
    int start = row_ptr[d], end = row_ptr[d + 1];
    size_t brow = (size_t)b * N_NODES;
    size_t drow = brow + d;
    float4 ed4 = ((const float4*)ed)[drow];
    float dx = 0.f, dy = 0.f, dz = 0.f, dw = 0.f;
    float acc[8] = {};
    const __half* hbase = Hf + (brow << 7) + (c8 << 3);
    for (int i0 = start; i0 < end; i0 += 64) {
        int nch = end - i0; if (nch > 64) nch = 64;
        WAVE_FENCE();   // WAR
        if (lane < nch) {
            int s = col[i0 + lane];
            colS[w][lane] = s;
            float4 e4 = ((const float4*)es)[brow + s];
            float l, a0, a1, a2, a3;
            l = e4.x + ed4.x; l = l > 0.f ? l : 0.2f * l; a0 = __expf(l); dx += a0;
            l = e4.y + ed4.y; l = l > 0.f ? l : 0.2f * l; a1 = __expf(l); dy += a1;
            l = e4.z + ed4.z; l = l > 0.f ? l : 0.2f * l; a2 = __expf(l); dz += a2;
            l = e4.w + ed4.w; l = l > 0.f ? l : 0.2f * l; a3 = __expf(l); dw += a3;
            *(float4*)&evS[w][lane][0] = make_float4(a0, a1, a2, a3);
        }
        WAVE_FENCE();   // RAW
        int nch8 = nch & ~7;
        for (int t = 0; t < nch8; t += 8) {   // guard-free: both slots valid
            int t0 = t + eg, t1 = t + 4 + eg;
            float a0 = evS[w][t0][head];
            float a1 = evS[w][t1][head];
            int s0 = colS[w][t0];
            int s1 = colS[w][t1];
            float4 r0 = *(const float4*)(hbase + ((size_t)s0 << 7));
            float4 r1 = *(const float4*)(hbase + ((size_t)s1 << 7));
            const unsigned* u0 = (const unsigned*)&r0;
            const unsigned* u1 = (const unsigned*)&r1;
            #pragma unroll
            for (int j = 0; j < 4; ++j) {
                FMA_MIX_LO(acc[2 * j],     u0[j], a0);
                FMA_MIX_HI(acc[2 * j + 1], u0[j], a0);
            }
            #pragma unroll
            for (int j = 0; j < 4; ++j) {
                FMA_MIX_LO(acc[2 * j],     u1[j], a1);
                FMA_MIX_HI(acc[2 * j + 1], u1[j], a1);
            }
        }
        if (nch8 < nch) {   // guarded tail (<=7 edges)
            int myt0 = nch8 + eg, myt1 = nch8 + 4 + eg;
            int tt0 = myt0 < nch ? myt0 : 0;
            int tt1 = myt1 < nch ? myt1 : 0;
            float a0 = evS[w][tt0][head]; if (myt0 >= nch) a0 = 0.f;
            float a1 = evS[w][tt1][head]; if (myt1 >= nch) a1 = 0.f;
            int s0 = colS[w][tt0];
            int s1 = colS[w][tt1];
            float4 r0 = *(const float4*)(hbase + ((size_t)s0 << 7));
            float4 r1 = *(const float4*)(hbase + ((size_t)s1 << 7));
            const unsigned* u0 = (const unsigned*)&r0;
            const unsigned* u1 = (const unsigned*)&r1;
            #pragma unroll
            for (int j = 0; j < 4; ++j) {
                FMA_MIX_LO(acc[2 * j],     u0[j], a0);
                FMA_MIX_HI(acc[2 * j + 1], u0[j], a0);
            }
            #pragma unroll
            for (int j = 0; j < 4; ++j) {
                FMA_MIX_LO(acc[2 * j],     u1[j], a1);
                FMA_MIX_HI(acc[2 * j + 1], u1[j], a1);
            }
        }
    }
    #pragma unroll
    for (int off = 32; off; off >>= 1) {
        dx += __shfl_xor(dx, off);
        dy += __shfl_xor(dy, off);
        dz += __shfl_xor(dz, off);
        dw += __shfl_xor(dw, off);
    }
    float ix = 1.f / (dx + 1e-9f);
    float iy = 1.f / (dy + 1e-9f);
    float iz = 1.f / (dz + 1e-9f);
    float iw = 1.f / (dw + 1e-9f);
    float inv = (head & 2) ? ((head & 1) ? iw : iz) : ((head & 1) ? iy : ix);
    #pragma unroll
    for (int j = 0; j < 8; ++j) {
        acc[j] += __shfl_xor(acc[j], 16);
        acc[j] += __shfl_xor(acc[j], 32);
    }
    if (eg == 0) {
        float4 b0 = *(const float4*)(bias + 8 * c8);
        float4 b1 = *(const float4*)(bias + 8 * c8 + 4);
        float vals[8];
        vals[0] = fmaxf(acc[0] * inv + b0.x, 0.f);
        vals[1] = fmaxf(acc[1] * inv + b0.y, 0.f);
        vals[2] = fmaxf(acc[2] * inv + b0.z, 0.f);
        vals[3] = fmaxf(acc[3] * inv + b0.w, 0.f);
        vals[4] = fmaxf(acc[4] * inv + b1.x, 0.f);
        vals[5] = fmaxf(acc[5] * inv + b1.y, 0.f);
        vals[6] = fmaxf(acc[6] * inv + b1.z, 0.f);
        vals[7] = fmaxf(acc[7] * inv + b1.w, 0.f);
        __half2 o[4];
        #pragma unroll
        for (int j = 0; j < 4; ++j) o[j] = __floats2half2_rn(vals[2 * j], vals[2 * j + 1]);
        *(float4*)(outH + drow * 128 + c8 * 8) = *(float4*)o;
    }
}

// ---------------- layer-2 aggregation (guard-free main loop, 2-edge unroll) -------
__global__ __launch_bounds__(512)
void agg2_kernel(const int* __restrict__ row_ptr, const int* __restrict__ col,
                 const float* __restrict__ es, const float* __restrict__ ed,
                 const __half* __restrict__ Hf, const float* __restrict__ bias,
                 float* __restrict__ outF) {
    __shared__ float evS[8][64];
    __shared__ int colS[8][64];
    int blk = blockIdx.x;
    int b = blk & 7;
    int grp = blk >> 3;
    int w = threadIdx.x >> 6;
    int d = grp * 8 + w;
    int lane = threadIdx.x & 63;
    int eg = lane >> 2;
    int c8 = lane & 3;
    int start = row_ptr[d], end = row_ptr[d + 1];
    size_t brow = (size_t)b * N_NODES;
    size_t drow = brow + d;
    float edv = ed[drow];
    float den = 0.f;
    float acc[8] = {};
    const __half* hbase = Hf + (brow << 5) + (c8 << 3);
    for (int i0 = start; i0 < end; i0 += 64) {
        int nch = end - i0; if (nch > 64) nch = 64;
        WAVE_FENCE();
        if (lane < nch) {
            int s = col[i0 + lane];
            colS[w][lane] = s;
            float l = es[brow + s] + edv;
            l = l > 0.f ? l : 0.2f * l;
            float ev = __expf(l);
            den += ev;
            evS[w][lane] = ev;
        }
        WAVE_FENCE();
        int nch32 = nch & ~31;
        for (int t = 0; t < nch32; t += 32) {
            int t0 = t + eg, t1 = t + 16 + eg;
            float a0 = evS[w][t0];
            float a1 = evS[w][t1];
            int s0 = colS[w][t0];
            int s1 = colS[w][t1];
            float4 r0 = *(const float4*)(hbase + ((size_t)s0 << 5));
            float4 r1 = *(const float4*)(hbase + ((size_t)s1 << 5));
            const unsigned* u0 = (const unsigned*)&r0;
            const unsigned* u1 = (const unsigned*)&r1;
            #pragma unroll
            for (int j = 0; j < 4; ++j) {
                FMA_MIX_LO(acc[2 * j],     u0[j], a0);
                FMA_MIX_HI(acc[2 * j + 1], u0[j], a0);
            }
            #pragma unroll
            for (int j = 0; j < 4; ++j) {
                FMA_MIX_LO(acc[2 * j],     u1[j], a1);
                FMA_MIX_HI(acc[2 * j + 1], u1[j], a1);
            }
        }
        if (nch32 < nch) {
            int myt0 = nch32 + eg, myt1 = nch32 + 16 + eg;
            int tt0 = myt0 < nch ? myt0 : 0;
            int tt1 = myt1 < nch ? myt1 : 0;
            float a0 = evS[w][tt0]; if (myt0 >= nch) a0 = 0.f;
            float a1 = evS[w][tt1]; if (myt1 >= nch) a1 = 0.f;
            int s0 = colS[w][tt0];
            int s1 = colS[w][tt1];
            float4 r0 = *(const float4*)(hbase + ((size_t)s0 << 5));
            float4 r1 = *(const float4*)(hbase + ((size_t)s1 << 5));
            const unsigned* u0 = (const unsigned*)&r0;
            const unsigned* u1 = (const unsigned*)&r1;
            #pragma unroll
            for (int j = 0; j < 4; ++j) {
                FMA_MIX_LO(acc[2 * j],     u0[j], a0);
                FMA_MIX_HI(acc[2 * j + 1], u0[j], a0);
            }
            #pragma unroll
            for (int j = 0; j < 4; ++j) {
                FMA_MIX_LO(acc[2 * j],     u1[j], a1);
                FMA_MIX_HI(acc[2 * j + 1], u1[j], a1);
            }
        }
    }
    #pragma unroll
    for (int off = 32; off; off >>= 1) den += __shfl_xor(den, off);
    float inv = 1.f / (den + 1e-9f);
    #pragma unroll
    for (int j = 0; j < 8; ++j) {
        acc[j] += __shfl_xor(acc[j], 4);
        acc[j] += __shfl_xor(acc[j], 8);
        acc[j] += __shfl_xor(acc[j], 16);
        acc[j] += __shfl_xor(acc[j], 32);
    }
    if (eg == 0) {
        float4 b0 = *(const float4*)(bias + 8 * c8);
        float4 b1 = *(const float4*)(bias + 8 * c8 + 4);
        float4 o0, o1;
        o0.x = acc[0] * inv + b0.x;
        o0.y = acc[1] * inv + b0.y;
        o0.z = acc[2] * inv + b0.z;
        o0.w = acc[3] * inv + b0.w;
        o1.x = acc[4] * inv + b1.x;
        o1.y = acc[5] * inv + b1.y;
        o1.z = acc[6] * inv + b1.z;
        o1.w = acc[7] * inv + b1.w;
        float* op = outF + drow * 32 + 8 * c8;
        *(float4*)op = o0;
        *(float4*)(op + 4) = o1;
    }
}

extern "C" void kernel_launch(void* const* d_in, const int* in_sizes, int n_in,
                              void* d_out, int out_size, void* d_ws, size_t ws_size,
                              hipStream_t stream) {
    const float* x    = (const float*)d_in[0];
    const int*   esrc = (const int*)d_in[1];
    const int*   edst = (const int*)d_in[2];
    const float* W1   = (const float*)d_in[3];
    const float* a1s  = (const float*)d_in[4];
    const float* a1d  = (const float*)d_in[5];
    const float* b1   = (const float*)d_in[6];
    const float* W2   = (const float*)d_in[7];
    const float* a2s  = (const float*)d_in[8];
    const float* a2d  = (const float*)d_in[9];
    const float* b2   = (const float*)d_in[10];
    float* out = (float*)d_out;
    const int E = in_sizes[1];
    const int rows = BATCH * N_NODES;  // 80000

    // workspace layout
    float* wsf = (float*)d_ws;
    __half* h1h   = (__half*)wsf;                       // rows*128 halfs
    float*  e1s   = wsf + (size_t)rows * 64;            // rows*4
    float*  e1d   = e1s + (size_t)rows * 4;             // rows*4
    __half* out1h = (__half*)(e1d + (size_t)rows * 4);  // rows*128 halfs
    int* deg      = (int*)((float*)out1h + (size_t)rows * 64);  // N
    int* cursor   = deg + N_NODES;                      // N
    int* row_ptr  = cursor + N_NODES;                   // N+1
    int* colIdx   = row_ptr + N_NODES + 1;              // E
    // layer 2 reuse
    __half* h2h = h1h;
    float*  e2s = e1s;
    float*  e2d = e1s + rows;

    const int TPB = 256;

    // ---------- CSR build (shared by both layers) ----------
    hipMemsetAsync(deg, 0, 2 * N_NODES * sizeof(int), stream);   // deg + cursor
    deg_kernel<<<(E + TPB - 1) / TPB, TPB, 0, stream>>>(edst, deg, E);
    scan_kernel<<<1, 1024, 0, stream>>>(deg, row_ptr, N_NODES);
    scatter_kernel<<<(E + TPB - 1) / TPB, TPB, 0, stream>>>(esrc, edst, row_ptr, cursor, colIdx, E);

    // ---------- layer 1 ----------
    gemm_att<float, FIN, 128, 32, 32, NH1><<<rows / 32, 256, 0, stream>>>(
        x, W1, a1s, a1d, h1h, e1s, e1d, rows);
    agg1_kernel<<<(N_NODES / 8) * BATCH, 512, 0, stream>>>(row_ptr, colIdx, e1s, e1d, h1h, b1, out1h);

    // ---------- layer 2 ----------
    gemm_att<__half, 128, UNITS, 128, 32, 1><<<rows / 128, 256, 0, stream>>>(
        out1h, W2, a2s, a2d, h2h, e2s, e2d, rows);
    agg2_kernel<<<(N_NODES / 8) * BATCH, 512, 0, stream>>>(row_ptr, colIdx, e2s, e2d, h2h, b2, out);
}

// Round 11
// 183.014 us; speedup vs baseline: 1.6813x; 1.1663x over previous
//
#include <hip/hip_runtime.h>
#include <hip/hip_fp16.h>

#define N_NODES 10000
#define BATCH 8
#define FIN 128
#define UNITS 32
#define NH1 4
#define MAXDEG 128   // padded bucket size; true max degree ~60 for E=330K random

#define WAVE_FENCE() asm volatile("s_waitcnt lgkmcnt(0)" ::: "memory")

// f16(lo/hi of u32) * f32 + f32 -> f32, one VOP3P instruction
#define FMA_MIX_LO(acc, u, a) \
    asm("v_fma_mix_f32 %0, %1, %2, %0 op_sel:[0,0,0] op_sel_hi:[1,0,0]" \
        : "+v"(acc) : "v"(u), "v"(a))
#define FMA_MIX_HI(acc, u, a) \
    asm("v_fma_mix_f32 %0, %1, %2, %0 op_sel:[1,0,0] op_sel_hi:[1,0,0]" \
        : "+v"(acc) : "v"(u), "v"(a))

// ---------------- vec4 loader (f32 or f16 source) ----------------
template<typename T> struct Vec4Loader;
template<> struct Vec4Loader<float> {
    static __device__ inline float4 load(const float* p) { return *(const float4*)p; }
};
template<> struct Vec4Loader<__half> {
    static __device__ inline float4 load(const __half* p) {
        const __half2* p2 = (const __half2*)p;
        float2 a = __half22float2(p2[0]);
        float2 b = __half22float2(p2[1]);
        return make_float4(a.x, a.y, b.x, b.y);
    }
};

// ---------------- register-tiled GEMM + register-space logits epilogue ------------
// TM rows x 4 cols per thread. Logits: acc[i][0..3] covers 4 cols of head h=cg>>3;
// reduce over the 8 threads (q=cg&7) sharing the head via shfl_xor 1/2/4.
template<typename XT, int K, int COLS, int BM, int KC, int TM, int H>
__global__ __launch_bounds__((BM / TM) * (COLS / 4))
void gemm_att(const XT* __restrict__ X, const float* __restrict__ W,
              const float* __restrict__ a_src, const float* __restrict__ a_dst,
              __half* __restrict__ Hout, float* __restrict__ es,
              float* __restrict__ ed, int rows) {
    constexpr int TN = 4;
    constexpr int NCG = COLS / TN;
    constexpr int NRG = BM / TM;
    constexpr int NT = NCG * NRG;
    constexpr int XPAD = BM + 4;
    __shared__ float Xs[KC][XPAD];
    __shared__ float Ws[KC][COLS];
    const int tid = threadIdx.x;
    const int cg = tid % NCG;
    const int rg = tid / NCG;
    const int row0 = blockIdx.x * BM;
    float acc[TM][TN] = {};
    for (int k0 = 0; k0 < K; k0 += KC) {
        const float4* wsrc = (const float4*)(W + (size_t)k0 * COLS);
        float4* wdst = (float4*)&Ws[0][0];
        #pragma unroll
        for (int idx = tid; idx < KC * COLS / 4; idx += NT) wdst[idx] = wsrc[idx];
        constexpr int F4R = KC / 4;
        #pragma unroll
        for (int idx = tid; idx < BM * F4R; idx += NT) {
            int row = idx / F4R, k4 = idx % F4R;
            float4 v = Vec4Loader<XT>::load(X + (size_t)(row0 + row) * K + k0 + 4 * k4);
            Xs[4 * k4 + 0][row] = v.x;
            Xs[4 * k4 + 1][row] = v.y;
            Xs[4 * k4 + 2][row] = v.z;
            Xs[4 * k4 + 3][row] = v.w;
        }
        __syncthreads();
        #pragma unroll
        for (int k = 0; k < KC; ++k) {
            float wr[TN], xr[TM];
            *(float4*)wr = *(const float4*)&Ws[k][TN * cg];
            #pragma unroll
            for (int q = 0; q < TM / 4; ++q)
                *(float4*)&xr[4 * q] = *(const float4*)&Xs[k][TM * rg + 4 * q];
            #pragma unroll
            for (int i = 0; i < TM; ++i)
                #pragma unroll
                for (int j = 0; j < TN; ++j)
                    acc[i][j] += xr[i] * wr[j];
        }
        __syncthreads();
    }
    // H-matrix write (f16)
    #pragma unroll
    for (int i = 0; i < TM; ++i) {
        int row = row0 + TM * rg + i;
        if (row < rows) {
            __half2 h01 = __floats2half2_rn(acc[i][0], acc[i][1]);
            __half2 h23 = __floats2half2_rn(acc[i][2], acc[i][3]);
            uint2 pk;
            pk.x = *reinterpret_cast<unsigned int*>(&h01);
            pk.y = *reinterpret_cast<unsigned int*>(&h23);
            *reinterpret_cast<uint2*>(Hout + (size_t)row * COLS + TN * cg) = pk;
        }
    }
    // fused logits: thread's cols = 32*h + 4*q + j
    int q = cg & 7, h = cg >> 3;
    float4 as4 = *(const float4*)(a_src + h * UNITS + 4 * q);
    float4 ad4 = *(const float4*)(a_dst + h * UNITS + 4 * q);
    #pragma unroll
    for (int i = 0; i < TM; ++i) {
        float esp = acc[i][0] * as4.x + acc[i][1] * as4.y
                  + acc[i][2] * as4.z + acc[i][3] * as4.w;
        float edp = acc[i][0] * ad4.x + acc[i][1] * ad4.y
                  + acc[i][2] * ad4.z + acc[i][3] * ad4.w;
        esp += __shfl_xor(esp, 1); esp += __shfl_xor(esp, 2); esp += __shfl_xor(esp, 4);
        edp += __shfl_xor(edp, 1); edp += __shfl_xor(edp, 2); edp += __shfl_xor(edp, 4);
        int row = row0 + TM * rg + i;
        if (q == 0 && row < rows) {
            es[(size_t)row * H + h] = esp;
            ed[(size_t)row * H + h] = edp;
        }
    }
}

// ---------------- padded-bucket adjacency build (no scan, no scatter) -------------
__global__ void build_kernel(const int* __restrict__ esrc, const int* __restrict__ edst,
                             int* __restrict__ deg, int* __restrict__ colPad, int E) {
    int e = blockIdx.x * blockDim.x + threadIdx.x;
    if (e >= E) return;
    int d = edst[e];
    int pos = atomicAdd(&deg[d], 1);
    colPad[(d << 7) + pos] = esrc[e];
}

// ---------------- layer-1 aggregation: single-phase, ILP-4 guard-free main loop ---
__global__ __launch_bounds__(512)
void agg1_kernel(const int* __restrict__ deg, const int* __restrict__ colPad,
                 const float* __restrict__ es, const float* __restrict__ ed,
                 const __half* __restrict__ Hf, const float* __restrict__ bias,
                 __half* __restrict__ outH) {
    __shared__ float evS[8][MAXDEG][4];   // 16 KB
    __shared__ int colS[8][MAXDEG];       // 4 KB
    int blk = blockIdx.x;
    int b = blk & 7;                  // batch -> XCD
    int grp = blk >> 3;
    int w = threadIdx.x >> 6;
    int d = grp * 8 + w;
    int lane = threadIdx.x & 63;
    int eg = lane >> 4;
    int c8 = lane & 15;
    int head = c8 >> 2;
    int n = deg[d];
    const int* colp = colPad + (d << 7);
    size_t brow = (size_t)b * N_NODES;
    size_t drow = brow + d;
    float4 ed4 = ((const float4*)ed)[drow];
    float dx = 0.f, dy = 0.f, dz = 0.f, dw = 0.f;
    // phase 1: alphas for all (<=128) edges
    #pragma unroll
    for (int rep = 0; rep < 2; ++rep) {
        int i = lane + rep * 64;
        if (i < n) {
            int s = colp[i];
            colS[w][i] = s;
            float4 e4 = ((const float4*)es)[brow + s];
            float l, a0, a1, a2, a3;
            l = e4.x + ed4.x; l = l > 0.f ? l : 0.2f * l; a0 = __expf(l); dx += a0;
            l = e4.y + ed4.y; l = l > 0.f ? l : 0.2f * l; a1 = __expf(l); dy += a1;
            l = e4.z + ed4.z; l = l > 0.f ? l : 0.2f * l; a2 = __expf(l); dz += a2;
            l = e4.w + ed4.w; l = l > 0.f ? l : 0.2f * l; a3 = __expf(l); dw += a3;
            *(float4*)&evS[w][i][0] = make_float4(a0, a1, a2, a3);
        }
    }
    WAVE_FENCE();   // wave-lockstep: all this wave's LDS writes drained
    // phase 2: guard-free ILP-4 accumulate (4 edges per eg-lane per iter)
    float acc[8] = {};
    const __half* hbase = Hf + (brow << 7) + (c8 << 3);
    int n16 = n & ~15;
    for (int t = 0; t < n16; t += 16) {
        int t0 = t + eg, t1 = t0 + 4, t2 = t0 + 8, t3 = t0 + 12;
        float a0 = evS[w][t0][head], a1 = evS[w][t1][head];
        float a2 = evS[w][t2][head], a3 = evS[w][t3][head];
        int s0 = colS[w][t0], s1 = colS[w][t1], s2 = colS[w][t2], s3 = colS[w][t3];
        float4 r0 = *(const float4*)(hbase + ((size_t)s0 << 7));
        float4 r1 = *(const float4*)(hbase + ((size_t)s1 << 7));
        float4 r2 = *(const float4*)(hbase + ((size_t)s2 << 7));
        float4 r3 = *(const float4*)(hbase + ((size_t)s3 << 7));
        const unsigned* u0 = (const unsigned*)&r0;
        const unsigned* u1 = (const unsigned*)&r1;
        const unsigned* u2 = (const unsigned*)&r2;
        const unsigned* u3 = (const unsigned*)&r3;
        #pragma unroll
        for (int j = 0; j < 4; ++j) {
            FMA_MIX_LO(acc[2 * j],     u0[j], a0);
            FMA_MIX_HI(acc[2 * j + 1], u0[j], a0);
        }
        #pragma unroll
        for (int j = 0; j < 4; ++j) {
            FMA_MIX_LO(acc[2 * j],     u1[j], a1);
            FMA_MIX_HI(acc[2 * j + 1], u1[j], a1);
        }
        #pragma unroll
        for (int j = 0; j < 4; ++j) {
            FMA_MIX_LO(acc[2 * j],     u2[j], a2);
            FMA_MIX_HI(acc[2 * j + 1], u2[j], a2);
        }
        #pragma unroll
        for (int j = 0; j < 4; ++j) {
            FMA_MIX_LO(acc[2 * j],     u3[j], a3);
            FMA_MIX_HI(acc[2 * j + 1], u3[j], a3);
        }
    }
    for (int t = n16; t < n; t += 4) {   // guarded tail, <=15 edges
        int myt = t + eg;
        int tt = myt < n ? myt : 0;
        float a = evS[w][tt][head]; if (myt >= n) a = 0.f;
        int s = colS[w][tt];
        float4 r = *(const float4*)(hbase + ((size_t)s << 7));
        const unsigned* u = (const unsigned*)&r;
        #pragma unroll
        for (int j = 0; j < 4; ++j) {
            FMA_MIX_LO(acc[2 * j],     u[j], a);
            FMA_MIX_HI(acc[2 * j + 1], u[j], a);
        }
    }
    #pragma unroll
    for (int off = 32; off; off >>= 1) {
        dx += __shfl_xor(dx, off);
        dy += __shfl_xor(dy, off);
        dz += __shfl_xor(dz, off);
        dw += __shfl_xor(dw, off);
    }
    float ix = 1.f / (dx + 1e-9f);
    float iy = 1.f / (dy + 1e-9f);
    float iz = 1.f / (dz + 1e-9f);
    float iw = 1.f / (dw + 1e-9f);
    float inv = (head & 2) ? ((head & 1) ? iw : iz) : ((head & 1) ? iy : ix);
    #pragma unroll
    for (int j = 0; j < 8; ++j) {
        acc[j] += __shfl_xor(acc[j], 16);
        acc[j] += __shfl_xor(acc[j], 32);
    }
    if (eg == 0) {
        float4 b0 = *(const float4*)(bias + 8 * c8);
        float4 b1 = *(const float4*)(bias + 8 * c8 + 4);
        float vals[8];
        vals[0] = fmaxf(acc[0] * inv + b0.x, 0.f);
        vals[1] = fmaxf(acc[1] * inv + b0.y, 0.f);
        vals[2] = fmaxf(acc[2] * inv + b0.z, 0.f);
        vals[3] = fmaxf(acc[3] * inv + b0.w, 0.f);
        vals[4] = fmaxf(acc[4] * inv + b1.x, 0.f);
        vals[5] = fmaxf(acc[5] * inv + b1.y, 0.f);
        vals[6] = fmaxf(acc[6] * inv + b1.z, 0.f);
        vals[7] = fmaxf(acc[7] * inv + b1.w, 0.f);
        __half2 o[4];
        #pragma unroll
        for (int j = 0; j < 4; ++j) o[j] = __floats2half2_rn(vals[2 * j], vals[2 * j + 1]);
        *(float4*)(outH + drow * 128 + c8 * 8) = *(float4*)o;
    }
}

// ---------------- layer-2 aggregation: single-phase, ILP-2 main loop --------------
__global__ __launch_bounds__(512)
void agg2_kernel(const int* __restrict__ deg, const int* __restrict__ colPad,
                 const float* __restrict__ es, const float* __restrict__ ed,
                 const __half* __restrict__ Hf, const float* __restrict__ bias,
                 float* __restrict__ outF) {
    __shared__ float evS[8][MAXDEG];   // 4 KB
    __shared__ int colS[8][MAXDEG];    // 4 KB
    int blk = blockIdx.x;
    int b = blk & 7;
    int grp = blk >> 3;
    int w = threadIdx.x >> 6;
    int d = grp * 8 + w;
    int lane = threadIdx.x & 63;
    int eg = lane >> 2;
    int c8 = lane & 3;
    int n = deg[d];
    const int* colp = colPad + (d << 7);
    size_t brow = (size_t)b * N_NODES;
    size_t drow = brow + d;
    float edv = ed[drow];
    float den = 0.f;
    #pragma unroll
    for (int rep = 0; rep < 2; ++rep) {
        int i = lane + rep * 64;
        if (i < n) {
            int s = colp[i];
            colS[w][i] = s;
            float l = es[brow + s] + edv;
            l = l > 0.f ? l : 0.2f * l;
            float ev = __expf(l);
            den += ev;
            evS[w][i] = ev;
        }
    }
    WAVE_FENCE();
    float acc[8] = {};
    const __half* hbase = Hf + (brow << 5) + (c8 << 3);
    int n32 = n & ~31;
    for (int t = 0; t < n32; t += 32) {
        int t0 = t + eg, t1 = t0 + 16;
        float a0 = evS[w][t0];
        float a1 = evS[w][t1];
        int s0 = colS[w][t0];
        int s1 = colS[w][t1];
        float4 r0 = *(const float4*)(hbase + ((size_t)s0 << 5));
        float4 r1 = *(const float4*)(hbase + ((size_t)s1 << 5));
        const unsigned* u0 = (const unsigned*)&r0;
        const unsigned* u1 = (const unsigned*)&r1;
        #pragma unroll
        for (int j = 0; j < 4; ++j) {
            FMA_MIX_LO(acc[2 * j],     u0[j], a0);
            FMA_MIX_HI(acc[2 * j + 1], u0[j], a0);
        }
        #pragma unroll
        for (int j = 0; j < 4; ++j) {
            FMA_MIX_LO(acc[2 * j],     u1[j], a1);
            FMA_MIX_HI(acc[2 * j + 1], u1[j], a1);
        }
    }
    for (int t = n32; t < n; t += 16) {   // guarded tail
        int myt = t + eg;
        int tt = myt < n ? myt : 0;
        float a = evS[w][tt]; if (myt >= n) a = 0.f;
        int s = colS[w][tt];
        float4 r = *(const float4*)(hbase + ((size_t)s << 5));
        const unsigned* u = (const unsigned*)&r;
        #pragma unroll
        for (int j = 0; j < 4; ++j) {
            FMA_MIX_LO(acc[2 * j],     u[j], a);
            FMA_MIX_HI(acc[2 * j + 1], u[j], a);
        }
    }
    #pragma unroll
    for (int off = 32; off; off >>= 1) den += __shfl_xor(den, off);
    float inv = 1.f / (den + 1e-9f);
    #pragma unroll
    for (int j = 0; j < 8; ++j) {
        acc[j] += __shfl_xor(acc[j], 4);
        acc[j] += __shfl_xor(acc[j], 8);
        acc[j] += __shfl_xor(acc[j], 16);
        acc[j] += __shfl_xor(acc[j], 32);
    }
    if (eg == 0) {
        float4 b0 = *(const float4*)(bias + 8 * c8);
        float4 b1 = *(const float4*)(bias + 8 * c8 + 4);
        float4 o0, o1;
        o0.x = acc[0] * inv + b0.x;
        o0.y = acc[1] * inv + b0.y;
        o0.z = acc[2] * inv + b0.z;
        o0.w = acc[3] * inv + b0.w;
        o1.x = acc[4] * inv + b1.x;
        o1.y = acc[5] * inv + b1.y;
        o1.z = acc[6] * inv + b1.z;
        o1.w = acc[7] * inv + b1.w;
        float* op = outF + drow * 32 + 8 * c8;
        *(float4*)op = o0;
        *(float4*)(op + 4) = o1;
    }
}

extern "C" void kernel_launch(void* const* d_in, const int* in_sizes, int n_in,
                              void* d_out, int out_size, void* d_ws, size_t ws_size,
                              hipStream_t stream) {
    const float* x    = (const float*)d_in[0];
    const int*   esrc = (const int*)d_in[1];
    const int*   edst = (const int*)d_in[2];
    const float* W1   = (const float*)d_in[3];
    const float* a1s  = (const float*)d_in[4];
    const float* a1d  = (const float*)d_in[5];
    const float* b1   = (const float*)d_in[6];
    const float* W2   = (const float*)d_in[7];
    const float* a2s  = (const float*)d_in[8];
    const float* a2d  = (const float*)d_in[9];
    const float* b2   = (const float*)d_in[10];
    float* out = (float*)d_out;
    const int E = in_sizes[1];
    const int rows = BATCH * N_NODES;  // 80000

    // workspace layout
    float* wsf = (float*)d_ws;
    __half* h1h   = (__half*)wsf;                       // rows*128 halfs
    float*  e1s   = wsf + (size_t)rows * 64;            // rows*4
    float*  e1d   = e1s + (size_t)rows * 4;             // rows*4
    __half* out1h = (__half*)(e1d + (size_t)rows * 4);  // rows*128 halfs
    int* deg      = (int*)((float*)out1h + (size_t)rows * 64);  // N
    int* colPad   = deg + N_NODES;                      // N*128
    // layer 2 reuse
    __half* h2h = h1h;
    float*  e2s = e1s;
    float*  e2d = e1s + rows;

    const int TPB = 256;

    // ---------- padded-bucket adjacency (shared by both layers) ----------
    hipMemsetAsync(deg, 0, N_NODES * sizeof(int), stream);
    build_kernel<<<(E + TPB - 1) / TPB, TPB, 0, stream>>>(esrc, edst, deg, colPad, E);

    // ---------- layer 1 ----------
    gemm_att<float, FIN, 128, 64, 32, 8, NH1><<<rows / 64, 256, 0, stream>>>(
        x, W1, a1s, a1d, h1h, e1s, e1d, rows);
    agg1_kernel<<<(N_NODES / 8) * BATCH, 512, 0, stream>>>(deg, colPad, e1s, e1d, h1h, b1, out1h);

    // ---------- layer 2 ----------
    gemm_att<__half, 128, UNITS, 128, 32, 4, 1><<<rows / 128, 256, 0, stream>>>(
        out1h, W2, a2s, a2d, h2h, e2s, e2d, rows);
    agg2_kernel<<<(N_NODES / 8) * BATCH, 512, 0, stream>>>(deg, colPad, e2s, e2d, h2h, b2, out);
}

// Round 12
// 154.604 us; speedup vs baseline: 1.9903x; 1.1838x over previous
//
#include <hip/hip_runtime.h>
#include <hip/hip_fp16.h>

#define N_NODES 10000
#define BATCH 8
#define FIN 128
#define UNITS 32
#define NH1 4
#define MAXDEG 128

#define WAVE_FENCE() asm volatile("s_waitcnt lgkmcnt(0)" ::: "memory")

#define FMA_MIX_LO(acc, u, a) \
    asm("v_fma_mix_f32 %0, %1, %2, %0 op_sel:[0,0,0] op_sel_hi:[1,0,0]" \
        : "+v"(acc) : "v"(u), "v"(a))
#define FMA_MIX_HI(acc, u, a) \
    asm("v_fma_mix_f32 %0, %1, %2, %0 op_sel:[1,0,0] op_sel_hi:[1,0,0]" \
        : "+v"(acc) : "v"(u), "v"(a))

typedef _Float16 half8 __attribute__((ext_vector_type(8)));
typedef float f32x4 __attribute__((ext_vector_type(4)));

// ---------------- prep: Wt1[144][128], Wt2[48][128] f16 (transposed W + logit cols) --
// Wt[c][k]; layer1: c<128 -> W1[k][c]; 128..131 -> sum_u W1[k][h][u]*a1s (h=c-128);
// 132..135 -> a1d; >=136 zero. layer2: c<32 -> W2[k][c]; 32 -> a2s dot; 33 -> a2d.
__global__ void prep_kernel(const float* __restrict__ W1, const float* __restrict__ a1s,
                            const float* __restrict__ a1d, const float* __restrict__ W2,
                            const float* __restrict__ a2s, const float* __restrict__ a2d,
                            __half* __restrict__ Wt1, __half* __restrict__ Wt2) {
    int t = blockIdx.x * blockDim.x + threadIdx.x;
    const int N1 = 144 * 128;
    if (t < N1) {
        int c = t >> 7, k = t & 127;
        float v = 0.f;
        if (c < 128) v = W1[k * 128 + c];
        else if (c < 132) {
            int h = c - 128;
            for (int u = 0; u < 32; ++u) v += W1[k * 128 + h * 32 + u] * a1s[h * 32 + u];
        } else if (c < 136) {
            int h = c - 132;
            for (int u = 0; u < 32; ++u) v += W1[k * 128 + h * 32 + u] * a1d[h * 32 + u];
        }
        Wt1[t] = __float2half(v);
    } else if (t < N1 + 48 * 128) {
        int q = t - N1;
        int c = q >> 7, k = q & 127;
        float v = 0.f;
        if (c < 32) v = W2[k * 32 + c];
        else if (c == 32) { for (int u = 0; u < 32; ++u) v += W2[k * 32 + u] * a2s[u]; }
        else if (c == 33) { for (int u = 0; u < 32; ++u) v += W2[k * 32 + u] * a2d[u]; }
        Wt2[q] = __float2half(v);
    }
}

// ---------------- MFMA GEMM + fused logit tile ----------------
// D[row][col] = X[row][:]·Wt[col][:]. 256 thr = 4 waves x 16 rows. K=128 (4 mfma steps).
// A: row=lane&15, k=8*(lane>>4)+j (global load, cvt if f32). B: col=lane&15 from LDS.
// D: col=lane&15, row=4*(lane>>4)+i (m89-verified). Tile HTILES holds es|ed columns.
template<typename XT, int NTILES, int HTILES, int ES>
__global__ __launch_bounds__(256)
void gemm_mfma(const XT* __restrict__ X, const __half* __restrict__ Wt,
               __half* __restrict__ Hout, float* __restrict__ es,
               float* __restrict__ ed, int rows) {
    constexpr int K = 128;
    constexpr int HCOLS = HTILES * 16;
    constexpr int PAD = 136;   // halfs per LDS row: 272 B -> 2-way banks on b128 reads
    __shared__ _Float16 Wl[NTILES * 16][PAD];
    const int tid = threadIdx.x;
    for (int idx = tid; idx < NTILES * 16 * K / 8; idx += 256) {
        int r = idx >> 4, kq = idx & 15;
        *(half8*)&Wl[r][kq * 8] = *(const half8*)(Wt + r * K + kq * 8);
    }
    __syncthreads();
    const int w = tid >> 6, lane = tid & 63;
    const int row16 = blockIdx.x * 64 + w * 16;
    const int arow = row16 + (lane & 15);
    const int cl = lane & 15;
    f32x4 acc[NTILES] = {};
    #pragma unroll
    for (int kb = 0; kb < 4; ++kb) {
        int kbase = kb * 32 + ((lane >> 4) << 3);
        half8 a;
        if constexpr (sizeof(XT) == 4) {
            const float* xp = (const float*)X + (size_t)arow * K + kbase;
            float4 v0 = *(const float4*)xp;
            float4 v1 = *(const float4*)(xp + 4);
            a[0] = v0.x; a[1] = v0.y; a[2] = v0.z; a[3] = v0.w;
            a[4] = v1.x; a[5] = v1.y; a[6] = v1.z; a[7] = v1.w;
        } else {
            a = *(const half8*)((const _Float16*)X + (size_t)arow * K + kbase);
        }
        #pragma unroll
        for (int t = 0; t < NTILES; ++t) {
            half8 b = *(const half8*)&Wl[t * 16 + cl][kbase];
            acc[t] = __builtin_amdgcn_mfma_f32_16x16x32_f16(a, b, acc[t], 0, 0, 0);
        }
    }
    const int rbase = row16 + ((lane >> 4) << 2);
    #pragma unroll
    for (int t = 0; t < HTILES; ++t) {
        #pragma unroll
        for (int i = 0; i < 4; ++i)
            Hout[(size_t)(rbase + i) * HCOLS + t * 16 + cl] = __float2half(acc[t][i]);
    }
    {   // logit tile
        f32x4 lg = acc[HTILES];
        if (cl < ES) {
            #pragma unroll
            for (int i = 0; i < 4; ++i) es[(size_t)(rbase + i) * ES + cl] = lg[i];
        } else if (cl < 2 * ES) {
            #pragma unroll
            for (int i = 0; i < 4; ++i) ed[(size_t)(rbase + i) * ES + (cl - ES)] = lg[i];
        }
    }
}

// ---------------- padded-bucket adjacency build ----------------
__global__ void build_kernel(const int* __restrict__ esrc, const int* __restrict__ edst,
                             int* __restrict__ deg, int* __restrict__ colPad, int E) {
    int e = blockIdx.x * blockDim.x + threadIdx.x;
    if (e >= E) return;
    int d = edst[e];
    int pos = atomicAdd(&deg[d], 1);
    colPad[(d << 7) + pos] = esrc[e];
}

// ---------------- layer-1 aggregation (unchanged from round 11) ----------------
__global__ __launch_bounds__(512)
void agg1_kernel(const int* __restrict__ deg, const int* __restrict__ colPad,
                 const float* __restrict__ es, const float* __restrict__ ed,
                 const __half* __restrict__ Hf, const float* __restrict__ bias,
                 __half* __restrict__ outH) {
    __shared__ float evS[8][MAXDEG][4];
    __shared__ int colS[8][MAXDEG];
    int blk = blockIdx.x;
    int b = blk & 7;
    int grp = blk >> 3;
    int w = threadIdx.x >> 6;
    int d = grp * 8 + w;
    int lane = threadIdx.x & 63;
    int eg = lane >> 4;
    int c8 = lane & 15;
    int head = c8 >> 2;
    int n = deg[d];
    const int* colp = colPad + (d << 7);
    size_t brow = (size_t)b * N_NODES;
    size_t drow = brow + d;
    float4 ed4 = ((const float4*)ed)[drow];
    float dx = 0.f, dy = 0.f, dz = 0.f, dw = 0.f;
    #pragma unroll
    for (int rep = 0; rep < 2; ++rep) {
        int i = lane + rep * 64;
        if (i < n) {
            int s = colp[i];
            colS[w][i] = s;
            float4 e4 = ((const float4*)es)[brow + s];
            float l, a0, a1, a2, a3;
            l = e4.x + ed4.x; l = l > 0.f ? l : 0.2f * l; a0 = __expf(l); dx += a0;
            l = e4.y + ed4.y; l = l > 0.f ? l : 0.2f * l; a1 = __expf(l); dy += a1;
            l = e4.z + ed4.z; l = l > 0.f ? l : 0.2f * l; a2 = __expf(l); dz += a2;
            l = e4.w + ed4.w; l = l > 0.f ? l : 0.2f * l; a3 = __expf(l); dw += a3;
            *(float4*)&evS[w][i][0] = make_float4(a0, a1, a2, a3);
        }
    }
    WAVE_FENCE();
    float acc[8] = {};
    const __half* hbase = Hf + (brow << 7) + (c8 << 3);
    int n16 = n & ~15;
    for (int t = 0; t < n16; t += 16) {
        int t0 = t + eg, t1 = t0 + 4, t2 = t0 + 8, t3 = t0 + 12;
        float a0 = evS[w][t0][head], a1 = evS[w][t1][head];
        float a2 = evS[w][t2][head], a3 = evS[w][t3][head];
        int s0 = colS[w][t0], s1 = colS[w][t1], s2 = colS[w][t2], s3 = colS[w][t3];
        float4 r0 = *(const float4*)(hbase + ((size_t)s0 << 7));
        float4 r1 = *(const float4*)(hbase + ((size_t)s1 << 7));
        float4 r2 = *(const float4*)(hbase + ((size_t)s2 << 7));
        float4 r3 = *(const float4*)(hbase + ((size_t)s3 << 7));
        const unsigned* u0 = (const unsigned*)&r0;
        const unsigned* u1 = (const unsigned*)&r1;
        const unsigned* u2 = (const unsigned*)&r2;
        const unsigned* u3 = (const unsigned*)&r3;
        #pragma unroll
        for (int j = 0; j < 4; ++j) {
            FMA_MIX_LO(acc[2 * j],     u0[j], a0);
            FMA_MIX_HI(acc[2 * j + 1], u0[j], a0);
        }
        #pragma unroll
        for (int j = 0; j < 4; ++j) {
            FMA_MIX_LO(acc[2 * j],     u1[j], a1);
            FMA_MIX_HI(acc[2 * j + 1], u1[j], a1);
        }
        #pragma unroll
        for (int j = 0; j < 4; ++j) {
            FMA_MIX_LO(acc[2 * j],     u2[j], a2);
            FMA_MIX_HI(acc[2 * j + 1], u2[j], a2);
        }
        #pragma unroll
        for (int j = 0; j < 4; ++j) {
            FMA_MIX_LO(acc[2 * j],     u3[j], a3);
            FMA_MIX_HI(acc[2 * j + 1], u3[j], a3);
        }
    }
    for (int t = n16; t < n; t += 4) {
        int myt = t + eg;
        int tt = myt < n ? myt : 0;
        float a = evS[w][tt][head]; if (myt >= n) a = 0.f;
        int s = colS[w][tt];
        float4 r = *(const float4*)(hbase + ((size_t)s << 7));
        const unsigned* u = (const unsigned*)&r;
        #pragma unroll
        for (int j = 0; j < 4; ++j) {
            FMA_MIX_LO(acc[2 * j],     u[j], a);
            FMA_MIX_HI(acc[2 * j + 1], u[j], a);
        }
    }
    #pragma unroll
    for (int off = 32; off; off >>= 1) {
        dx += __shfl_xor(dx, off);
        dy += __shfl_xor(dy, off);
        dz += __shfl_xor(dz, off);
        dw += __shfl_xor(dw, off);
    }
    float ix = 1.f / (dx + 1e-9f);
    float iy = 1.f / (dy + 1e-9f);
    float iz = 1.f / (dz + 1e-9f);
    float iw = 1.f / (dw + 1e-9f);
    float inv = (head & 2) ? ((head & 1) ? iw : iz) : ((head & 1) ? iy : ix);
    #pragma unroll
    for (int j = 0; j < 8; ++j) {
        acc[j] += __shfl_xor(acc[j], 16);
        acc[j] += __shfl_xor(acc[j], 32);
    }
    if (eg == 0) {
        float4 b0 = *(const float4*)(bias + 8 * c8);
        float4 b1 = *(const float4*)(bias + 8 * c8 + 4);
        float vals[8];
        vals[0] = fmaxf(acc[0] * inv + b0.x, 0.f);
        vals[1] = fmaxf(acc[1] * inv + b0.y, 0.f);
        vals[2] = fmaxf(acc[2] * inv + b0.z, 0.f);
        vals[3] = fmaxf(acc[3] * inv + b0.w, 0.f);
        vals[4] = fmaxf(acc[4] * inv + b1.x, 0.f);
        vals[5] = fmaxf(acc[5] * inv + b1.y, 0.f);
        vals[6] = fmaxf(acc[6] * inv + b1.z, 0.f);
        vals[7] = fmaxf(acc[7] * inv + b1.w, 0.f);
        __half2 o[4];
        #pragma unroll
        for (int j = 0; j < 4; ++j) o[j] = __floats2half2_rn(vals[2 * j], vals[2 * j + 1]);
        *(float4*)(outH + drow * 128 + c8 * 8) = *(float4*)o;
    }
}

// ---------------- layer-2 aggregation (unchanged from round 11) ----------------
__global__ __launch_bounds__(512)
void agg2_kernel(const int* __restrict__ deg, const int* __restrict__ colPad,
                 const float* __restrict__ es, const float* __restrict__ ed,
                 const __half* __restrict__ Hf, const float* __restrict__ bias,
                 float* __restrict__ outF) {
    __shared__ float evS[8][MAXDEG];
    __shared__ int colS[8][MAXDEG];
    int blk = blockIdx.x;
    int b = blk & 7;
    int grp = blk >> 3;
    int w = threadIdx.x >> 6;
    int d = grp * 8 + w;
    int lane = threadIdx.x & 63;
    int eg = lane >> 2;
    int c8 = lane & 3;
    int n = deg[d];
    const int* colp = colPad + (d << 7);
    size_t brow = (size_t)b * N_NODES;
    size_t drow = brow + d;
    float edv = ed[drow];
    float den = 0.f;
    #pragma unroll
    for (int rep = 0; rep < 2; ++rep) {
        int i = lane + rep * 64;
        if (i < n) {
            int s = colp[i];
            colS[w][i] = s;
            float l = es[brow + s] + edv;
            l = l > 0.f ? l : 0.2f * l;
            float ev = __expf(l);
            den += ev;
            evS[w][i] = ev;
        }
    }
    WAVE_FENCE();
    float acc[8] = {};
    const __half* hbase = Hf + (brow << 5) + (c8 << 3);
    int n32 = n & ~31;
    for (int t = 0; t < n32; t += 32) {
        int t0 = t + eg, t1 = t0 + 16;
        float a0 = evS[w][t0];
        float a1 = evS[w][t1];
        int s0 = colS[w][t0];
        int s1 = colS[w][t1];
        float4 r0 = *(const float4*)(hbase + ((size_t)s0 << 5));
        float4 r1 = *(const float4*)(hbase + ((size_t)s1 << 5));
        const unsigned* u0 = (const unsigned*)&r0;
        const unsigned* u1 = (const unsigned*)&r1;
        #pragma unroll
        for (int j = 0; j < 4; ++j) {
            FMA_MIX_LO(acc[2 * j],     u0[j], a0);
            FMA_MIX_HI(acc[2 * j + 1], u0[j], a0);
        }
        #pragma unroll
        for (int j = 0; j < 4; ++j) {
            FMA_MIX_LO(acc[2 * j],     u1[j], a1);
            FMA_MIX_HI(acc[2 * j + 1], u1[j], a1);
        }
    }
    for (int t = n32; t < n; t += 16) {
        int myt = t + eg;
        int tt = myt < n ? myt : 0;
        float a = evS[w][tt]; if (myt >= n) a = 0.f;
        int s = colS[w][tt];
        float4 r = *(const float4*)(hbase + ((size_t)s << 5));
        const unsigned* u = (const unsigned*)&r;
        #pragma unroll
        for (int j = 0; j < 4; ++j) {
            FMA_MIX_LO(acc[2 * j],     u[j], a);
            FMA_MIX_HI(acc[2 * j + 1], u[j], a);
        }
    }
    #pragma unroll
    for (int off = 32; off; off >>= 1) den += __shfl_xor(den, off);
    float inv = 1.f / (den + 1e-9f);
    #pragma unroll
    for (int j = 0; j < 8; ++j) {
        acc[j] += __shfl_xor(acc[j], 4);
        acc[j] += __shfl_xor(acc[j], 8);
        acc[j] += __shfl_xor(acc[j], 16);
        acc[j] += __shfl_xor(acc[j], 32);
    }
    if (eg == 0) {
        float4 b0 = *(const float4*)(bias + 8 * c8);
        float4 b1 = *(const float4*)(bias + 8 * c8 + 4);
        float4 o0, o1;
        o0.x = acc[0] * inv + b0.x;
        o0.y = acc[1] * inv + b0.y;
        o0.z = acc[2] * inv + b0.z;
        o0.w = acc[3] * inv + b0.w;
        o1.x = acc[4] * inv + b1.x;
        o1.y = acc[5] * inv + b1.y;
        o1.z = acc[6] * inv + b1.z;
        o1.w = acc[7] * inv + b1.w;
        float* op = outF + drow * 32 + 8 * c8;
        *(float4*)op = o0;
        *(float4*)(op + 4) = o1;
    }
}

extern "C" void kernel_launch(void* const* d_in, const int* in_sizes, int n_in,
                              void* d_out, int out_size, void* d_ws, size_t ws_size,
                              hipStream_t stream) {
    const float* x    = (const float*)d_in[0];
    const int*   esrc = (const int*)d_in[1];
    const int*   edst = (const int*)d_in[2];
    const float* W1   = (const float*)d_in[3];
    const float* a1s  = (const float*)d_in[4];
    const float* a1d  = (const float*)d_in[5];
    const float* b1   = (const float*)d_in[6];
    const float* W2   = (const float*)d_in[7];
    const float* a2s  = (const float*)d_in[8];
    const float* a2d  = (const float*)d_in[9];
    const float* b2   = (const float*)d_in[10];
    float* out = (float*)d_out;
    const int E = in_sizes[1];
    const int rows = BATCH * N_NODES;  // 80000

    // workspace layout
    float* wsf = (float*)d_ws;
    __half* h1h   = (__half*)wsf;                       // rows*128 halfs
    float*  e1s   = wsf + (size_t)rows * 64;            // rows*4
    float*  e1d   = e1s + (size_t)rows * 4;             // rows*4
    __half* out1h = (__half*)(e1d + (size_t)rows * 4);  // rows*128 halfs
    int* deg      = (int*)((float*)out1h + (size_t)rows * 64);  // N
    int* colPad   = deg + N_NODES;                      // N*128
    __half* Wt1   = (__half*)(colPad + N_NODES * 128);  // 144*128 halfs
    __half* Wt2   = Wt1 + 144 * 128;                    // 48*128 halfs
    // layer 2 reuse
    __half* h2h = h1h;
    float*  e2s = e1s;
    float*  e2d = e1s + rows;

    const int TPB = 256;

    // ---------- prep + adjacency ----------
    hipMemsetAsync(deg, 0, N_NODES * sizeof(int), stream);
    prep_kernel<<<(144 * 128 + 48 * 128 + TPB - 1) / TPB, TPB, 0, stream>>>(
        W1, a1s, a1d, W2, a2s, a2d, Wt1, Wt2);
    build_kernel<<<(E + TPB - 1) / TPB, TPB, 0, stream>>>(esrc, edst, deg, colPad, E);

    // ---------- layer 1 ----------
    gemm_mfma<float, 9, 8, 4><<<rows / 64, 256, 0, stream>>>(
        x, Wt1, h1h, e1s, e1d, rows);
    agg1_kernel<<<(N_NODES / 8) * BATCH, 512, 0, stream>>>(deg, colPad, e1s, e1d, h1h, b1, out1h);

    // ---------- layer 2 ----------
    gemm_mfma<__half, 3, 2, 1><<<rows / 64, 256, 0, stream>>>(
        out1h, Wt2, h2h, e2s, e2d, rows);
    agg2_kernel<<<(N_NODES / 8) * BATCH, 512, 0, stream>>>(deg, colPad, e2s, e2d, h2h, b2, out);
}